// Round 17
// baseline (166.278 us; speedup 1.0000x reference)
//
#include <hip/hip_runtime.h>
#include <hip/hip_bf16.h>

typedef unsigned short u16;
typedef __attribute__((ext_vector_type(8))) short short8;
typedef __attribute__((ext_vector_type(4))) float float4v;

#define BATCH 8
#define SLEN  200
#define NNODE 512
#define NEDGE 2048
#define NEGV  -9000000000000000.0f

#define H1GR 212   // h1g rows per node: 2 pad + 200 data + 10 pad
#define H1GS 32    // h1g row stride in bf16 (64 B)

__device__ __forceinline__ u16 f2bf(float f) {
    unsigned int x = __float_as_uint(f);
    unsigned int lsb = (x >> 16) & 1u;
    x += 0x7fffu + lsb;
    return (u16)(x >> 16);
}

__device__ __forceinline__ float bf2f(u16 u) {
    return __uint_as_float(((unsigned int)u) << 16);
}

__device__ __forceinline__ unsigned int pk2(float a, float b) {
    __hip_bfloat162 h = __float22bfloat162_rn(make_float2(a, b));
    unsigned int r;
    __builtin_memcpy(&r, &h, 4);
    return r;
}

// ---------------------------------------------------------------------------
// pre_kernel (67 blocks):
//   blk 0: w2f pack ; 1: efw ; 2: w2gf (flat per-element, round-12 lesson)
//   blk >= 3: adj bitmask, one u16 chunk/thread (64 blocks)
// ---------------------------------------------------------------------------
__global__ __launch_bounds__(256) void pre_kernel(
    const int* __restrict__ adj,     // (512, 512)
    const float* __restrict__ w2,    // (64, 32, 5) conv2
    const float* __restrict__ fc1w,  // (128, 64)
    const float* __restrict__ W2g,   // (64, 64) GAT layer-2 W
    u16* __restrict__ w2f,           // 20*64*8
    u16* __restrict__ efw,           // 16*64*8
    u16* __restrict__ w2gf,          // 8*64*8
    u16* __restrict__ msk)           // 512*32 u16
{
    const int t = threadIdx.x;
    const int blk = blockIdx.x;

    if (blk == 0) {
        // conv2 B-frags: fid = kk*4+ot ; oc = ot*16+ml ; col c = q*8+j,
        // ic = (c&1)*16 + (c>>1)  (interleaved h1 layout)
        for (int idx = t; idx < 20 * 64 * 8; idx += 256) {
            const int fid = idx >> 9, rem = idx & 511;
            const int lane = rem >> 3, j = rem & 7;
            const int kk = fid >> 2, ot = fid & 3;
            const int ml = lane & 15, q = lane >> 4;
            const int c  = q * 8 + j;
            const int ic = (c & 1) * 16 + (c >> 1);
            const int oc = ot * 16 + ml;
            w2f[idx] = f2bf(w2[(size_t)oc * 160 + ic * 5 + kk]);
        }
        return;
    }
    if (blk == 1) {
        for (int idx = t; idx < 16 * 64 * 8; idx += 256) {
            const int u = idx >> 9, rem = idx & 511;
            const int lane = rem >> 3, j = rem & 7;
            const int ks = u >> 2, wvv = u & 3;
            const int ml = lane & 15, q = lane >> 4;
            const int o = wvv * 16 + ml;
            const int k = ks * 32 + q * 8 + j;
            efw[idx] = f2bf(fc1w[k * 64 + o]);
        }
        return;
    }
    if (blk == 2) {
        for (int idx = t; idx < 8 * 64 * 8; idx += 256) {
            const int u = idx >> 9, rem = idx & 511;
            const int lane = rem >> 3, j = rem & 7;
            const int kh = u >> 2, nt = u & 3;
            const int ml = lane & 15, q = lane >> 4;
            const int o = nt * 16 + ml;
            const int k = kh * 32 + q * 8 + j;
            w2gf[idx] = f2bf(W2g[k * 64 + o]);
        }
        return;
    }

    {
        const int tid   = (blk - 3) * 256 + t;        // 0..16383
        const int row   = tid >> 5;
        const int chunk = tid & 31;
        const int4* ap = (const int4*)(adj + (size_t)row * 512 + chunk * 16);
        const int4 a0 = ap[0], a1 = ap[1], a2 = ap[2], a3 = ap[3];
        unsigned int bits = 0;
        bits |= (a0.x > 0) ? 0x0001u : 0u;  bits |= (a0.y > 0) ? 0x0002u : 0u;
        bits |= (a0.z > 0) ? 0x0004u : 0u;  bits |= (a0.w > 0) ? 0x0008u : 0u;
        bits |= (a1.x > 0) ? 0x0010u : 0u;  bits |= (a1.y > 0) ? 0x0020u : 0u;
        bits |= (a1.z > 0) ? 0x0040u : 0u;  bits |= (a1.w > 0) ? 0x0080u : 0u;
        bits |= (a2.x > 0) ? 0x0100u : 0u;  bits |= (a2.y > 0) ? 0x0200u : 0u;
        bits |= (a2.z > 0) ? 0x0400u : 0u;  bits |= (a2.w > 0) ? 0x0800u : 0u;
        bits |= (a3.x > 0) ? 0x1000u : 0u;  bits |= (a3.y > 0) ? 0x2000u : 0u;
        bits |= (a3.z > 0) ? 0x4000u : 0u;  bits |= (a3.w > 0) ? 0x8000u : 0u;
        msk[row * 32 + chunk] = (u16)bits;
    }
}

// ---------------------------------------------------------------------------
// conv1_kernel: VALU f32 conv1 -> h1g (global bf16, interleaved columns).
// 2 nodes/block, 2048 blocks x 256 thr. NO h1 LDS: thread (p,g) stores u32
// at row (2+s), col 2p -> 16-lane groups write 64 B-coalesced rows.
// (Round-16 lesson: conv's barrier phase-chain was the floor; split kernels
// run each phase at its own resource's speed.)
// ---------------------------------------------------------------------------
__global__ __launch_bounds__(256) void conv1_kernel(
    const float* __restrict__ x,    // (8, 200, 1024)
    const float* __restrict__ w1,   // (32, 2, 5)
    const float* __restrict__ b1,   // (32,)
    u16* __restrict__ h1g)          // (4096, 212, 32) bf16
{
    __shared__ float xs[2][2][212];                 // [node][ch][s+2], pads 0

    const int t    = threadIdx.x;
    const int blk  = blockIdx.x;
    const int b    = blk >> 8;
    const int pair = blk & 255;
    const int p = t & 15;
    const int g = t >> 4;
    const int ng0 = b * 512 + pair * 2;             // global node id of nd=0

    float wA[10], wB[10];
    #pragma unroll
    for (int j = 0; j < 10; ++j) {
        wA[j] = w1[p * 10 + j];
        wB[j] = w1[(16 + p) * 10 + j];
    }
    const float b1a = b1[p], b1b = b1[16 + p];

    // stage x for BOTH nodes: one float4 = cols 4*pair..4*pair+3 at row (b,t)
    if (t < SLEN) {
        const float4 xv = *(const float4*)(x + ((size_t)(b * SLEN + t)) * 1024 + 4 * pair);
        xs[0][0][2 + t] = xv.x;
        xs[0][1][2 + t] = xv.y;
        xs[1][0][2 + t] = xv.z;
        xs[1][1][2 + t] = xv.w;
    } else if (t < 212) {
        const int pp = (t < 202) ? (t - 200) : t;
        xs[0][0][pp] = 0.f; xs[0][1][pp] = 0.f;
        xs[1][0][pp] = 0.f; xs[1][1][pp] = 0.f;
    }

    // zero pad rows in h1g: rows 0,1 (u32 0..31) + 202..211 (u32 3232..3391)
    {
        unsigned int* hg32 = (unsigned int*)h1g;
        for (int idx = t; idx < 384; idx += 256) {
            const int nd = (idx >= 192);
            const int i2 = idx - nd * 192;
            const int off = (i2 < 32) ? i2 : (202 * 16 + (i2 - 32));
            hg32[(size_t)(ng0 + nd) * (H1GR * 16) + off] = 0u;
        }
    }
    __syncthreads();

    unsigned int* hg32 = (unsigned int*)h1g;
    #pragma unroll
    for (int nd = 0; nd < 2; ++nd) {
        const size_t nbase = (size_t)(ng0 + nd) * (H1GR * 16);
        #pragma unroll
        for (int u = 0; u < 4; ++u) {
            const int base = 4 * g + 64 * u;
            if (base < SLEN) {
                float X0[8], X1[8];
                *(float4*)&X0[0] = *(const float4*)&xs[nd][0][base];
                *(float4*)&X0[4] = *(const float4*)&xs[nd][0][base + 4];
                *(float4*)&X1[0] = *(const float4*)&xs[nd][1][base];
                *(float4*)&X1[4] = *(const float4*)&xs[nd][1][base + 4];
                #pragma unroll
                for (int i = 0; i < 4; ++i) {
                    float a0 = b1a, a1v = b1b;
                    #pragma unroll
                    for (int k = 0; k < 5; ++k) {
                        const float x0 = X0[i + k], x1 = X1[i + k];
                        a0  += wA[k] * x0 + wA[5 + k] * x1;
                        a1v += wB[k] * x0 + wB[5 + k] * x1;
                    }
                    // interleaved: col 2p = ic p (low), 2p+1 = ic 16+p (high)
                    hg32[nbase + (2 + base + i) * 16 + p] =
                        pk2(fmaxf(a0, 0.f), fmaxf(a1v, 0.f));
                }
            }
        }
    }
}

// ---------------------------------------------------------------------------
// conv2_kernel: 1 node/block, 4096 blocks x 256 thr. A-fragments read
// directly from global h1g (wave reads contiguous 1 KB windows, L2-hot).
// 16x16x32 MFMA -> relu -> mean -> Wh1/f1/f2 (round-11 epilogue). ~2 KB LDS.
// ---------------------------------------------------------------------------
__global__ __launch_bounds__(256) void conv2_kernel(
    const u16* __restrict__ h1g,    // (4096, 212, 32) bf16
    const float* __restrict__ b2,   // (64,)
    const float* __restrict__ W1,   // (64, 64)
    const float* __restrict__ a1,   // (128, 1)
    const u16* __restrict__ w2f,
    u16* __restrict__ Wh_bt,        // (8, 64, 512) bf16 [b][o][node]
    float* __restrict__ f1,         // (4096,)
    float* __restrict__ f2)         // (4096,)
{
    __shared__ float red[4][32];
    __shared__ float hm[64];
    __shared__ float part[4][64];

    const int t    = threadIdx.x;
    const int blk  = blockIdx.x;        // global node id = b*512 + n
    const int b    = blk >> 9;
    const int n    = blk & 511;
    const int lane = t & 63;
    const int wv   = t >> 6;
    const int ml   = lane & 15;
    const int q    = lane >> 4;
    const int o2 = wv & 1;
    const int mh = wv >> 1;

    short8 wfA[5], wfB[5];
    #pragma unroll
    for (int kk = 0; kk < 5; ++kk) {
        wfA[kk] = *(const short8*)(w2f + ((kk * 4 + o2 * 2 + 0) * 64 + lane) * 8);
        wfB[kk] = *(const short8*)(w2f + ((kk * 4 + o2 * 2 + 1) * 64 + lane) * 8);
    }
    const float bias2a = b2[o2 * 32 + ml];
    const float bias2b = b2[o2 * 32 + 16 + ml];

    const u16* hb = h1g + (size_t)blk * (H1GR * H1GS);

    // conv2 via 16x16x32 MFMA: wave = (o2, mh); m-tiles [mh*7, mh?13:7)
    float tA = 0.f, tB = 0.f;
    const int mt0 = mh * 7, mtE = mh ? 13 : 7;
    for (int mt = mt0; mt < mtE; ++mt) {
        float4v acc0 = {0.f, 0.f, 0.f, 0.f};
        float4v acc1 = {0.f, 0.f, 0.f, 0.f};
        #pragma unroll
        for (int kk = 0; kk < 5; ++kk) {
            const short8 a = *(const short8*)(hb + (mt * 16 + ml + kk) * H1GS + q * 8);
            acc0 = __builtin_amdgcn_mfma_f32_16x16x32_bf16(a, wfA[kk], acc0, 0, 0, 0);
            acc1 = __builtin_amdgcn_mfma_f32_16x16x32_bf16(a, wfB[kk], acc1, 0, 0, 0);
        }
        if (mt < 12) {
            #pragma unroll
            for (int r = 0; r < 4; ++r) {
                tA += fmaxf(acc0[r] + bias2a, 0.f);
                tB += fmaxf(acc1[r] + bias2b, 0.f);
            }
        } else if (q < 2) {   // m = 192 + q*4 + r < 200
            #pragma unroll
            for (int r = 0; r < 4; ++r) {
                tA += fmaxf(acc0[r] + bias2a, 0.f);
                tB += fmaxf(acc1[r] + bias2b, 0.f);
            }
        }
    }
    tA += __shfl_xor(tA, 16, 64);
    tA += __shfl_xor(tA, 32, 64);
    tB += __shfl_xor(tB, 16, 64);
    tB += __shfl_xor(tB, 32, 64);
    if (lane < 16) {
        red[wv][ml]      = tA;     // oc = o2*32 + ml
        red[wv][16 + ml] = tB;     // oc = o2*32 + 16 + ml
    }
    __syncthreads();
    if (t < 64) {
        const int grp = t >> 5, idx = t & 31;      // waves grp, grp+2 hold this oc
        hm[t] = (red[grp][idx] + red[grp + 2][idx]) * (1.0f / 200.0f);
    }
    __syncthreads();

    // fused Wh1 = hm @ W1 (f32), + f1/f2 dots
    {
        const int o = t & 63, q4 = t >> 6;
        const float* Wp = W1 + (q4 * 16) * 64 + o;
        float pv = 0.f;
        #pragma unroll
        for (int k = 0; k < 16; ++k) pv += hm[q4 * 16 + k] * Wp[k * 64];
        part[q4][o] = pv;
    }
    __syncthreads();
    if (t < 64) {
        const float v = part[0][t] + part[1][t] + part[2][t] + part[3][t];
        Wh_bt[((size_t)(b * 64 + t)) * 512 + n] = f2bf(v);
        float v1 = v * a1[t];
        float v2 = v * a1[64 + t];
        #pragma unroll
        for (int off = 32; off; off >>= 1) {
            v1 += __shfl_xor(v1, off, 64);
            v2 += __shfl_xor(v2, off, 64);
        }
        if (t == 0) { f1[b * 512 + n] = v1; f2[b * 512 + n] = v2; }
    }
}

// ---------------------------------------------------------------------------
// gat_attn_kernel: 16-row i-tiles, 512 threads, bitmask phase 1, B-fragment
// register prefetch. fuse=1: epilogue computes Wh2 = relu(out)@W2 + f1/f2.
// fuse=0: writes outp (no relu). (Round-15 lesson: separate launches beat
// cooperative grid.sync by ~100 us on this device.)
// ---------------------------------------------------------------------------
#define PSTR 520
__global__ __launch_bounds__(512) void gat_attn_kernel(
    const u16* __restrict__ Wh_bt,   // (8, 64, 512) bf16
    const float* __restrict__ f1in,
    const float* __restrict__ f2in,
    const u16* __restrict__ msk,     // (512, 32) u16 bitmask
    const u16* __restrict__ w2gf,    // GAT-W2 B-frags (fuse=1)
    const float* __restrict__ a2,    // (128,)       (fuse=1)
    u16* __restrict__ whbt_out,      // (8, 64, 512) (fuse=1)
    float* __restrict__ f1out,       //              (fuse=1)
    float* __restrict__ f2out,       //              (fuse=1)
    float* __restrict__ outp,        // (4096, 64)   (fuse=0)
    const int fuse)
{
    __shared__ __align__(16) u16 P[16 * PSTR];
    __shared__ float f2s[512];
    __shared__ float invs[16];
    __shared__ float f1s[16];
    __shared__ float accH[4][64][4];
    __shared__ __align__(16) u16 g1s[16 * 72];
    __shared__ __align__(16) u16 wh2s[64 * 20];
    __shared__ float fp1[4][16], fp2[4][16];

    const int t   = threadIdx.x;
    const int blk = blockIdx.x;
    const int b   = blk >> 5;
    const int i0  = (blk & 31) * 16;
    const int lane = t & 63, wv = t >> 6, nt = wv & 3, kh = wv >> 2;
    const int ml = lane & 15, q = lane >> 4;

    // prefetch B fragments for phase 2 (issue before softmax work)
    const u16* Bp = Wh_bt + ((size_t)(b * 64 + nt * 16 + ml)) * 512 + kh * 256 + q * 8;
    short8 bfr[8];
    #pragma unroll
    for (int ks = 0; ks < 8; ++ks)
        bfr[ks] = *(const short8*)(Bp + ks * 32);

    f2s[t & 511] = f2in[b * 512 + (t & 511)];
    if (t < 16) f1s[t] = f1in[b * 512 + i0 + t];
    __syncthreads();

    // phase 1: thread = (i = t>>5, jseg = t&31) -> 16 j's via one u16 of mask
    {
        const int i = t >> 5, jseg = t & 31;
        const float f1i = f1s[i];
        const unsigned int mbits = msk[(size_t)(i0 + i) * 32 + jseg];
        const float* f2p = f2s + jseg * 16;
        float ev[16];
        float mx = -3.0e38f;
        #pragma unroll
        for (int v = 0; v < 16; ++v) {
            float e = f1i + f2p[v];
            e = e > 0.f ? e : 0.2f * e;
            e = ((mbits >> v) & 1u) ? e : NEGV;
            ev[v] = e;
            mx = fmaxf(mx, e);
        }
        mx = fmaxf(mx, __shfl_xor(mx, 1, 64));
        mx = fmaxf(mx, __shfl_xor(mx, 2, 64));
        mx = fmaxf(mx, __shfl_xor(mx, 4, 64));
        mx = fmaxf(mx, __shfl_xor(mx, 8, 64));
        mx = fmaxf(mx, __shfl_xor(mx, 16, 64));
        float sum = 0.f;
        #pragma unroll
        for (int v = 0; v < 16; ++v) {
            const float ex = __expf(ev[v] - mx);
            ev[v] = ex;
            sum += ex;
        }
        sum += __shfl_xor(sum, 1, 64);
        sum += __shfl_xor(sum, 2, 64);
        sum += __shfl_xor(sum, 4, 64);
        sum += __shfl_xor(sum, 8, 64);
        sum += __shfl_xor(sum, 16, 64);
        if (jseg == 0) invs[i] = 1.0f / sum;
        unsigned int* prow = (unsigned int*)&P[i * PSTR + jseg * 16];
        #pragma unroll
        for (int v = 0; v < 8; ++v)
            prow[v] = pk2(ev[2 * v], ev[2 * v + 1]);
    }
    __syncthreads();

    // phase 2: out(16x64) = P(16x512) @ Wh(512x64); wave = (nt, kh)
    float4v acc = {0.f, 0.f, 0.f, 0.f};
    #pragma unroll
    for (int ks = 0; ks < 8; ++ks) {
        const short8 afr = *(const short8*)&P[ml * PSTR + kh * 256 + ks * 32 + q * 8];
        acc = __builtin_amdgcn_mfma_f32_16x16x32_bf16(afr, bfr[ks], acc, 0, 0, 0);
    }
    if (kh == 1) {
        #pragma unroll
        for (int r = 0; r < 4; ++r) accH[nt][lane][r] = acc[r];
    }
    __syncthreads();
    if (kh == 0) {
        #pragma unroll
        for (int r = 0; r < 4; ++r) {
            const int i2 = q * 4 + r;
            float val = (acc[r] + accH[nt][lane][r]) * invs[i2];
            if (fuse) {
                val = fmaxf(val, 0.f);
                g1s[i2 * 72 + nt * 16 + ml] = f2bf(val);
            } else {
                outp[((size_t)(b * 512 + i0 + i2)) * 64 + nt * 16 + ml] = val;
            }
        }
    }

    if (!fuse) return;

    // fused layer-2 Wh: Wh2(16x64) = g1s @ W2 ; wave = (nt, kh), 1 MFMA each
    __syncthreads();
    const short8 af2 = *(const short8*)&g1s[ml * 72 + kh * 32 + q * 8];
    const short8 bf2v = *(const short8*)(w2gf + ((kh * 4 + nt) * 64 + lane) * 8);
    float4v c2 = {0.f, 0.f, 0.f, 0.f};
    c2 = __builtin_amdgcn_mfma_f32_16x16x32_bf16(af2, bf2v, c2, 0, 0, 0);
    if (kh == 1) {
        #pragma unroll
        for (int r = 0; r < 4; ++r) accH[nt][lane][r] = c2[r];
    }
    __syncthreads();
    if (kh == 0) {
        const int o = nt * 16 + ml;
        const float a2o1 = a2[o], a2o2 = a2[64 + o];
        #pragma unroll
        for (int r = 0; r < 4; ++r) {
            const float wv2 = c2[r] + accH[nt][lane][r];
            wh2s[o * 20 + q * 4 + r] = f2bf(wv2);
            float p1 = wv2 * a2o1, p2 = wv2 * a2o2;
            p1 += __shfl_xor(p1, 1, 64); p2 += __shfl_xor(p2, 1, 64);
            p1 += __shfl_xor(p1, 2, 64); p2 += __shfl_xor(p2, 2, 64);
            p1 += __shfl_xor(p1, 4, 64); p2 += __shfl_xor(p2, 4, 64);
            p1 += __shfl_xor(p1, 8, 64); p2 += __shfl_xor(p2, 8, 64);
            if (ml == 0) {
                fp1[nt][q * 4 + r] = p1;
                fp2[nt][q * 4 + r] = p2;
            }
        }
    }
    __syncthreads();
    if (t < 256) {
        const int o = t >> 2, seg = t & 3;
        *(uint2*)&whbt_out[((size_t)(b * 64 + o)) * 512 + i0 + seg * 4] =
            *(const uint2*)&wh2s[o * 20 + seg * 4];
    }
    if (t < 16) {
        f1out[b * 512 + i0 + t] = fp1[0][t] + fp1[1][t] + fp1[2][t] + fp1[3][t];
        f2out[b * 512 + i0 + t] = fp2[0][t] + fp2[1][t] + fp2[2][t] + fp2[3][t];
    }
}

// ---------------------------------------------------------------------------
// Kernel: edge MLP via MFMA, 16 edges/block, prepacked fc1 B-fragments
// ---------------------------------------------------------------------------
#define FSTR 136
__global__ __launch_bounds__(256) void edge_mlp_kernel(
    const float* __restrict__ hg,       // (4096, 64)
    const int* __restrict__ eidx,       // (2048, 2)
    const u16* __restrict__ efw,        // prepacked fc1 B-frags
    const float* __restrict__ fc1b,     // (64,)
    const float* __restrict__ fc2w,     // (64, 1)
    const float* __restrict__ fc2b,     // (1,)
    float* __restrict__ out)            // (8, 2048)
{
    __shared__ __align__(16) u16 he[16 * FSTR];
    __shared__ float part[16][4];

    const int t   = threadIdx.x;
    const int blk = blockIdx.x;
    const int b   = blk >> 7;
    const int e0  = (blk & 127) * 16;
    const int lane = t & 63, wv = t >> 6, ml = lane & 15, q = lane >> 4;

    short8 bw[4];
    #pragma unroll
    for (int ks = 0; ks < 4; ++ks)
        bw[ks] = *(const short8*)(efw + ((ks * 4 + wv) * 64 + lane) * 8);
    const int o = 16 * wv + ml;
    const float bo = fc1b[o];
    const float wo = fc2w[o];

    {
        const int ep = t >> 4, p = t & 15;
        const int e = e0 + ep;
        const int node = (p < 8) ? eidx[e * 2] : eidx[e * 2 + 1];
        const int c0 = (p & 7) * 8;
        const float* hp = hg + ((size_t)(b * 512 + node)) * 64 + c0;
        const float4 fa = *(const float4*)hp;
        const float4 fb = *(const float4*)(hp + 4);
        unsigned int* dst = (unsigned int*)&he[ep * FSTR + ((p < 8) ? 0 : 64) + c0];
        dst[0] = pk2(fa.x, fa.y);
        dst[1] = pk2(fa.z, fa.w);
        dst[2] = pk2(fb.x, fb.y);
        dst[3] = pk2(fb.z, fb.w);
    }
    __syncthreads();

    float4v acc = {0.f, 0.f, 0.f, 0.f};
    #pragma unroll
    for (int ks = 0; ks < 4; ++ks) {
        const short8 afr = *(const short8*)&he[ml * FSTR + ks * 32 + q * 8];
        acc = __builtin_amdgcn_mfma_f32_16x16x32_bf16(afr, bw[ks], acc, 0, 0, 0);
    }
    #pragma unroll
    for (int r = 0; r < 4; ++r) {
        float z = fmaxf(acc[r] + bo, 0.f) * wo;
        z += __shfl_xor(z, 1, 64);
        z += __shfl_xor(z, 2, 64);
        z += __shfl_xor(z, 4, 64);
        z += __shfl_xor(z, 8, 64);
        if (ml == 0) part[q * 4 + r][wv] = z;
    }
    __syncthreads();
    if (t < 16) {
        const float v = part[t][0] + part[t][1] + part[t][2] + part[t][3] + fc2b[0];
        out[b * 2048 + e0 + t] = 1.0f / (1.0f + __expf(-v));
    }
}

// ---------------------------------------------------------------------------
extern "C" void kernel_launch(void* const* d_in, const int* in_sizes, int n_in,
                              void* d_out, int out_size, void* d_ws, size_t ws_size,
                              hipStream_t stream) {
    const float* x    = (const float*)d_in[0];
    const int* adj    = (const int*)d_in[1];
    const int* eidx   = (const int*)d_in[2];
    const float* w1   = (const float*)d_in[3];
    const float* b1   = (const float*)d_in[4];
    const float* w2   = (const float*)d_in[5];
    const float* b2   = (const float*)d_in[6];
    const float* W1   = (const float*)d_in[7];
    const float* a1   = (const float*)d_in[8];
    const float* W2   = (const float*)d_in[9];
    const float* a2   = (const float*)d_in[10];
    const float* fc1w = (const float*)d_in[11];
    const float* fc1b = (const float*)d_in[12];
    const float* fc2w = (const float*)d_in[13];
    const float* fc2b = (const float*)d_in[14];
    float* out = (float*)d_out;

    float* ws = (float*)d_ws;
    const size_t R = (size_t)BATCH * NNODE;       // 4096
    float* g     = ws;                            // R*64 f32 (layer-2 out)
    float* f1a   = g + R * 64;                    // R
    float* f2a   = f1a + R;                       // R
    float* f1b   = f2a + R;                       // R
    float* f2b   = f1b + R;                       // R
    u16*   whbt1 = (u16*)(f2b + R);               // R*64
    u16*   whbt2 = whbt1 + R * 64;                // R*64
    u16*   w2f   = whbt2 + R * 64;                // 10240
    u16*   efw   = w2f + 10240;                   // 8192
    u16*   w2gf  = efw + 8192;                    // 4096
    u16*   msk   = w2gf + 4096;                   // 16384 u16 (32 KB)
    u16*   h1g   = msk + 16384;                   // 4096*212*32 u16 (55.6 MB)

    pre_kernel<<<dim3(67), dim3(256), 0, stream>>>(
        adj, w2, fc1w, W2, w2f, efw, w2gf, msk);
    conv1_kernel<<<dim3(2048), dim3(256), 0, stream>>>(x, w1, b1, h1g);
    conv2_kernel<<<dim3(4096), dim3(256), 0, stream>>>(
        h1g, b2, W1, a1, w2f, whbt1, f1a, f2a);
    gat_attn_kernel<<<dim3(256), dim3(512), 0, stream>>>(
        whbt1, f1a, f2a, msk, w2gf, a2, whbt2, f1b, f2b, g, 1);
    gat_attn_kernel<<<dim3(256), dim3(512), 0, stream>>>(
        whbt2, f1b, f2b, msk, w2gf, a2, whbt2, f1b, f2b, g, 0);
    edge_mlp_kernel<<<dim3(1024), dim3(256), 0, stream>>>(
        g, eidx, efw, fc1b, fc2w, fc2b, out);
}

// Round 18
// 135.035 us; speedup vs baseline: 1.2314x; 1.2314x over previous
//
#include <hip/hip_runtime.h>
#include <hip/hip_bf16.h>

typedef unsigned short u16;
typedef __attribute__((ext_vector_type(8))) short short8;
typedef __attribute__((ext_vector_type(4))) float float4v;

#define BATCH 8
#define SLEN  200
#define NNODE 512
#define NEDGE 2048
#define NEGV  -9000000000000000.0f

#define H1S 40    // h1p row stride in bf16 (80 B; 20-dword bank shift/row)
#define H1R 212   // 2 pad + 200 data + 10 pad

__device__ __forceinline__ u16 f2bf(float f) {
    unsigned int x = __float_as_uint(f);
    unsigned int lsb = (x >> 16) & 1u;
    x += 0x7fffu + lsb;
    return (u16)(x >> 16);
}

__device__ __forceinline__ float bf2f(u16 u) {
    return __uint_as_float(((unsigned int)u) << 16);
}

__device__ __forceinline__ unsigned int pk2(float a, float b) {
    __hip_bfloat162 h = __float22bfloat162_rn(make_float2(a, b));
    unsigned int r;
    __builtin_memcpy(&r, &h, 4);
    return r;
}

// ---------------------------------------------------------------------------
// pre_kernel (67 blocks — no transpose; conv reads x directly):
//   blk 0: w2f pack ; 1: efw ; 2: w2gf (flat per-element, round-12 lesson)
//   blk >= 3: adj bitmask, one u16 chunk/thread (64 blocks)
// ---------------------------------------------------------------------------
__global__ __launch_bounds__(256) void pre_kernel(
    const int* __restrict__ adj,     // (512, 512)
    const float* __restrict__ w2,    // (64, 32, 5) conv2
    const float* __restrict__ fc1w,  // (128, 64)
    const float* __restrict__ W2g,   // (64, 64) GAT layer-2 W
    u16* __restrict__ w2f,           // 20*64*8
    u16* __restrict__ efw,           // 16*64*8
    u16* __restrict__ w2gf,          // 8*64*8
    u16* __restrict__ msk)           // 512*32 u16
{
    const int t = threadIdx.x;
    const int blk = blockIdx.x;

    if (blk == 0) {
        for (int idx = t; idx < 20 * 64 * 8; idx += 256) {
            const int fid = idx >> 9, rem = idx & 511;
            const int lane = rem >> 3, j = rem & 7;
            const int kk = fid >> 2, ot = fid & 3;
            const int ml = lane & 15, q = lane >> 4;
            const int c  = q * 8 + j;
            const int ic = (c & 1) * 16 + (c >> 1);
            const int oc = ot * 16 + ml;
            w2f[idx] = f2bf(w2[(size_t)oc * 160 + ic * 5 + kk]);
        }
        return;
    }
    if (blk == 1) {
        for (int idx = t; idx < 16 * 64 * 8; idx += 256) {
            const int u = idx >> 9, rem = idx & 511;
            const int lane = rem >> 3, j = rem & 7;
            const int ks = u >> 2, wvv = u & 3;
            const int ml = lane & 15, q = lane >> 4;
            const int o = wvv * 16 + ml;
            const int k = ks * 32 + q * 8 + j;
            efw[idx] = f2bf(fc1w[k * 64 + o]);
        }
        return;
    }
    if (blk == 2) {
        for (int idx = t; idx < 8 * 64 * 8; idx += 256) {
            const int u = idx >> 9, rem = idx & 511;
            const int lane = rem >> 3, j = rem & 7;
            const int kh = u >> 2, nt = u & 3;
            const int ml = lane & 15, q = lane >> 4;
            const int o = nt * 16 + ml;
            const int k = kh * 32 + q * 8 + j;
            w2gf[idx] = f2bf(W2g[k * 64 + o]);
        }
        return;
    }

    {
        const int tid   = (blk - 3) * 256 + t;        // 0..16383
        const int row   = tid >> 5;
        const int chunk = tid & 31;
        const int4* ap = (const int4*)(adj + (size_t)row * 512 + chunk * 16);
        const int4 a0 = ap[0], a1 = ap[1], a2 = ap[2], a3 = ap[3];
        unsigned int bits = 0;
        bits |= (a0.x > 0) ? 0x0001u : 0u;  bits |= (a0.y > 0) ? 0x0002u : 0u;
        bits |= (a0.z > 0) ? 0x0004u : 0u;  bits |= (a0.w > 0) ? 0x0008u : 0u;
        bits |= (a1.x > 0) ? 0x0010u : 0u;  bits |= (a1.y > 0) ? 0x0020u : 0u;
        bits |= (a1.z > 0) ? 0x0040u : 0u;  bits |= (a1.w > 0) ? 0x0080u : 0u;
        bits |= (a2.x > 0) ? 0x0100u : 0u;  bits |= (a2.y > 0) ? 0x0200u : 0u;
        bits |= (a2.z > 0) ? 0x0400u : 0u;  bits |= (a2.w > 0) ? 0x0800u : 0u;
        bits |= (a3.x > 0) ? 0x1000u : 0u;  bits |= (a3.y > 0) ? 0x2000u : 0u;
        bits |= (a3.z > 0) ? 0x4000u : 0u;  bits |= (a3.w > 0) ? 0x8000u : 0u;
        msk[row * 32 + chunk] = (u16)bits;
    }
}

// ---------------------------------------------------------------------------
// conv_fused_kernel: 2 nodes/block, shared h1p, direct x read (no xT).
// grid 2048 x 256 thr. (Round-17 lesson: h1 must stay in LDS — the global
// detour pays cross-XCD miss latency; all split/fusion variants falsified.)
// ---------------------------------------------------------------------------
__global__ __launch_bounds__(256) void conv_fused_kernel(
    const float* __restrict__ x,    // (8, 200, 1024)
    const float* __restrict__ w1,   // (32, 2, 5)
    const float* __restrict__ b1,   // (32,)
    const float* __restrict__ b2,   // (64,)
    const float* __restrict__ W1,   // (64, 64)
    const float* __restrict__ a1,   // (128, 1)
    const u16* __restrict__ w2f,
    u16* __restrict__ Wh_bt,        // (8, 64, 512) bf16 [b][o][node]
    float* __restrict__ f1,         // (4096,)
    float* __restrict__ f2)         // (4096,)
{
    __shared__ float xs[2][2][212];                 // [node][ch][s+2], pads 0
    __shared__ __align__(16) u16 h1p[H1R * H1S];    // shared across nodes
    __shared__ float red[4][2][32];
    __shared__ float hm[2][64];
    __shared__ float part[2][4][64];

    const int t    = threadIdx.x;
    const int blk  = blockIdx.x;
    const int b    = blk >> 8;
    const int pair = blk & 255;
    const int n0   = pair * 2;
    const int lane = t & 63;
    const int wv   = t >> 6;
    const int ml   = lane & 15;
    const int q    = lane >> 4;
    const int p = t & 15;
    const int g = t >> 4;
    const int o2 = wv & 1;
    const int mh = wv >> 1;

    short8 wfA[5], wfB[5];
    #pragma unroll
    for (int kk = 0; kk < 5; ++kk) {
        wfA[kk] = *(const short8*)(w2f + ((kk * 4 + o2 * 2 + 0) * 64 + lane) * 8);
        wfB[kk] = *(const short8*)(w2f + ((kk * 4 + o2 * 2 + 1) * 64 + lane) * 8);
    }
    const float bias2a = b2[o2 * 32 + ml];
    const float bias2b = b2[o2 * 32 + 16 + ml];

    float wA[10], wB[10];
    #pragma unroll
    for (int j = 0; j < 10; ++j) {
        wA[j] = w1[p * 10 + j];
        wB[j] = w1[(16 + p) * 10 + j];
    }
    const float b1a = b1[p], b1b = b1[16 + p];

    // stage x for BOTH nodes: one float4 = cols 4*pair..4*pair+3 at row (b,t)
    if (t < SLEN) {
        const float4 xv = *(const float4*)(x + ((size_t)(b * SLEN + t)) * 1024 + 4 * pair);
        xs[0][0][2 + t] = xv.x;
        xs[0][1][2 + t] = xv.y;
        xs[1][0][2 + t] = xv.z;
        xs[1][1][2 + t] = xv.w;
    } else if (t < 212) {
        const int pp = (t < 202) ? (t - 200) : t;
        xs[0][0][pp] = 0.f; xs[0][1][pp] = 0.f;
        xs[1][0][pp] = 0.f; xs[1][1][pp] = 0.f;
    }
    {
        unsigned int* hz = (unsigned int*)h1p;
        if (t < 40)       hz[t] = 0u;
        else if (t < 240) hz[4000 + t] = 0u;      // rows 202..211
    }
    __syncthreads();

    float tAn[2], tBn[2];
    for (int nd = 0; nd < 2; ++nd) {
        // conv1 (VALU f32) -> h1p
        #pragma unroll
        for (int u = 0; u < 4; ++u) {
            const int base = 4 * g + 64 * u;
            if (base < SLEN) {
                float X0[8], X1[8];
                *(float4*)&X0[0] = *(const float4*)&xs[nd][0][base];
                *(float4*)&X0[4] = *(const float4*)&xs[nd][0][base + 4];
                *(float4*)&X1[0] = *(const float4*)&xs[nd][1][base];
                *(float4*)&X1[4] = *(const float4*)&xs[nd][1][base + 4];
                #pragma unroll
                for (int i = 0; i < 4; ++i) {
                    float a0 = b1a, a1v = b1b;
                    #pragma unroll
                    for (int k = 0; k < 5; ++k) {
                        const float x0 = X0[i + k], x1 = X1[i + k];
                        a0  += wA[k] * x0 + wA[5 + k] * x1;
                        a1v += wB[k] * x0 + wB[5 + k] * x1;
                    }
                    *(unsigned int*)&h1p[(2 + base + i) * H1S + 2 * p] =
                        pk2(fmaxf(a0, 0.f), fmaxf(a1v, 0.f));
                }
            }
        }
        __syncthreads();

        // conv2 via 16x16x32 MFMA: wave = (o2, mh); m-tiles [mh*7, mh?13:7)
        float tA = 0.f, tB = 0.f;
        const int mt0 = mh * 7, mtE = mh ? 13 : 7;
        for (int mt = mt0; mt < mtE; ++mt) {
            float4v acc0 = {0.f, 0.f, 0.f, 0.f};
            float4v acc1 = {0.f, 0.f, 0.f, 0.f};
            #pragma unroll
            for (int kk = 0; kk < 5; ++kk) {
                const short8 a = *(const short8*)&h1p[(mt * 16 + ml + kk) * H1S + q * 8];
                acc0 = __builtin_amdgcn_mfma_f32_16x16x32_bf16(a, wfA[kk], acc0, 0, 0, 0);
                acc1 = __builtin_amdgcn_mfma_f32_16x16x32_bf16(a, wfB[kk], acc1, 0, 0, 0);
            }
            if (mt < 12) {
                #pragma unroll
                for (int r = 0; r < 4; ++r) {
                    tA += fmaxf(acc0[r] + bias2a, 0.f);
                    tB += fmaxf(acc1[r] + bias2b, 0.f);
                }
            } else if (q < 2) {   // m = 192 + q*4 + r < 200
                #pragma unroll
                for (int r = 0; r < 4; ++r) {
                    tA += fmaxf(acc0[r] + bias2a, 0.f);
                    tB += fmaxf(acc1[r] + bias2b, 0.f);
                }
            }
        }
        tA += __shfl_xor(tA, 16, 64);
        tA += __shfl_xor(tA, 32, 64);
        tB += __shfl_xor(tB, 16, 64);
        tB += __shfl_xor(tB, 32, 64);
        tAn[nd] = tA;
        tBn[nd] = tB;
        __syncthreads();   // protect h1p before next node's conv1 overwrite
    }

    if (lane < 16) {
        red[wv][0][ml]      = tAn[0];   // oc = o2*32 + ml
        red[wv][0][16 + ml] = tBn[0];   // oc = o2*32 + 16 + ml
        red[wv][1][ml]      = tAn[1];
        red[wv][1][16 + ml] = tBn[1];
    }
    __syncthreads();
    if (t < 128) {
        const int nd = t >> 6, o = t & 63;
        const int grp = (o >> 5), idx = o & 31;   // waves grp, grp+2 hold this oc
        hm[nd][o] = (red[grp][nd][idx] + red[grp + 2][nd][idx]) * (1.0f / 200.0f);
    }
    __syncthreads();

    // fused Wh1 = hm @ W1 (f32); both nodes share the W1 column loads
    {
        const int o = t & 63, q4 = t >> 6;
        const float* Wp = W1 + (q4 * 16) * 64 + o;
        float p0 = 0.f, p1 = 0.f;
        #pragma unroll
        for (int k = 0; k < 16; ++k) {
            const float w = Wp[k * 64];
            p0 += hm[0][q4 * 16 + k] * w;
            p1 += hm[1][q4 * 16 + k] * w;
        }
        part[0][q4][o] = p0;
        part[1][q4][o] = p1;
    }
    __syncthreads();
    if (t < 128) {
        const int nd = t >> 6, o = t & 63;
        const int n = n0 + nd;
        const float v = part[nd][0][o] + part[nd][1][o] + part[nd][2][o] + part[nd][3][o];
        Wh_bt[((size_t)(b * 64 + o)) * 512 + n] = f2bf(v);
        float v1 = v * a1[o];
        float v2 = v * a1[64 + o];
        #pragma unroll
        for (int off = 32; off; off >>= 1) {
            v1 += __shfl_xor(v1, off, 64);
            v2 += __shfl_xor(v2, off, 64);
        }
        if (o == 0) { f1[b * 512 + n] = v1; f2[b * 512 + n] = v2; }
    }
}

// ---------------------------------------------------------------------------
// gat_attn_kernel: 16-row i-tiles, 512 threads, bitmask phase 1, B-fragment
// register prefetch. fuse=1: epilogue computes Wh2 = relu(out)@W2 + f1/f2.
// fuse=0: writes outp (no relu). (Round-15 lesson: separate launches beat
// cooperative grid.sync by ~100 us on this device.)
// ---------------------------------------------------------------------------
#define PSTR 520
__global__ __launch_bounds__(512) void gat_attn_kernel(
    const u16* __restrict__ Wh_bt,   // (8, 64, 512) bf16
    const float* __restrict__ f1in,
    const float* __restrict__ f2in,
    const u16* __restrict__ msk,     // (512, 32) u16 bitmask
    const u16* __restrict__ w2gf,    // GAT-W2 B-frags (fuse=1)
    const float* __restrict__ a2,    // (128,)       (fuse=1)
    u16* __restrict__ whbt_out,      // (8, 64, 512) (fuse=1)
    float* __restrict__ f1out,       //              (fuse=1)
    float* __restrict__ f2out,       //              (fuse=1)
    float* __restrict__ outp,        // (4096, 64)   (fuse=0)
    const int fuse)
{
    __shared__ __align__(16) u16 P[16 * PSTR];
    __shared__ float f2s[512];
    __shared__ float invs[16];
    __shared__ float f1s[16];
    __shared__ float accH[4][64][4];
    __shared__ __align__(16) u16 g1s[16 * 72];
    __shared__ __align__(16) u16 wh2s[64 * 20];
    __shared__ float fp1[4][16], fp2[4][16];

    const int t   = threadIdx.x;
    const int blk = blockIdx.x;
    const int b   = blk >> 5;
    const int i0  = (blk & 31) * 16;
    const int lane = t & 63, wv = t >> 6, nt = wv & 3, kh = wv >> 2;
    const int ml = lane & 15, q = lane >> 4;

    // prefetch B fragments for phase 2 (issue before softmax work)
    const u16* Bp = Wh_bt + ((size_t)(b * 64 + nt * 16 + ml)) * 512 + kh * 256 + q * 8;
    short8 bfr[8];
    #pragma unroll
    for (int ks = 0; ks < 8; ++ks)
        bfr[ks] = *(const short8*)(Bp + ks * 32);

    f2s[t & 511] = f2in[b * 512 + (t & 511)];
    if (t < 16) f1s[t] = f1in[b * 512 + i0 + t];
    __syncthreads();

    // phase 1: thread = (i = t>>5, jseg = t&31) -> 16 j's via one u16 of mask
    {
        const int i = t >> 5, jseg = t & 31;
        const float f1i = f1s[i];
        const unsigned int mbits = msk[(size_t)(i0 + i) * 32 + jseg];
        const float* f2p = f2s + jseg * 16;
        float ev[16];
        float mx = -3.0e38f;
        #pragma unroll
        for (int v = 0; v < 16; ++v) {
            float e = f1i + f2p[v];
            e = e > 0.f ? e : 0.2f * e;
            e = ((mbits >> v) & 1u) ? e : NEGV;
            ev[v] = e;
            mx = fmaxf(mx, e);
        }
        mx = fmaxf(mx, __shfl_xor(mx, 1, 64));
        mx = fmaxf(mx, __shfl_xor(mx, 2, 64));
        mx = fmaxf(mx, __shfl_xor(mx, 4, 64));
        mx = fmaxf(mx, __shfl_xor(mx, 8, 64));
        mx = fmaxf(mx, __shfl_xor(mx, 16, 64));
        float sum = 0.f;
        #pragma unroll
        for (int v = 0; v < 16; ++v) {
            const float ex = __expf(ev[v] - mx);
            ev[v] = ex;
            sum += ex;
        }
        sum += __shfl_xor(sum, 1, 64);
        sum += __shfl_xor(sum, 2, 64);
        sum += __shfl_xor(sum, 4, 64);
        sum += __shfl_xor(sum, 8, 64);
        sum += __shfl_xor(sum, 16, 64);
        if (jseg == 0) invs[i] = 1.0f / sum;
        unsigned int* prow = (unsigned int*)&P[i * PSTR + jseg * 16];
        #pragma unroll
        for (int v = 0; v < 8; ++v)
            prow[v] = pk2(ev[2 * v], ev[2 * v + 1]);
    }
    __syncthreads();

    // phase 2: out(16x64) = P(16x512) @ Wh(512x64); wave = (nt, kh)
    float4v acc = {0.f, 0.f, 0.f, 0.f};
    #pragma unroll
    for (int ks = 0; ks < 8; ++ks) {
        const short8 afr = *(const short8*)&P[ml * PSTR + kh * 256 + ks * 32 + q * 8];
        acc = __builtin_amdgcn_mfma_f32_16x16x32_bf16(afr, bfr[ks], acc, 0, 0, 0);
    }
    if (kh == 1) {
        #pragma unroll
        for (int r = 0; r < 4; ++r) accH[nt][lane][r] = acc[r];
    }
    __syncthreads();
    if (kh == 0) {
        #pragma unroll
        for (int r = 0; r < 4; ++r) {
            const int i2 = q * 4 + r;
            float val = (acc[r] + accH[nt][lane][r]) * invs[i2];
            if (fuse) {
                val = fmaxf(val, 0.f);
                g1s[i2 * 72 + nt * 16 + ml] = f2bf(val);
            } else {
                outp[((size_t)(b * 512 + i0 + i2)) * 64 + nt * 16 + ml] = val;
            }
        }
    }

    if (!fuse) return;

    // fused layer-2 Wh: Wh2(16x64) = g1s @ W2 ; wave = (nt, kh), 1 MFMA each
    __syncthreads();
    const short8 af2 = *(const short8*)&g1s[ml * 72 + kh * 32 + q * 8];
    const short8 bf2v = *(const short8*)(w2gf + ((kh * 4 + nt) * 64 + lane) * 8);
    float4v c2 = {0.f, 0.f, 0.f, 0.f};
    c2 = __builtin_amdgcn_mfma_f32_16x16x32_bf16(af2, bf2v, c2, 0, 0, 0);
    if (kh == 1) {
        #pragma unroll
        for (int r = 0; r < 4; ++r) accH[nt][lane][r] = c2[r];
    }
    __syncthreads();
    if (kh == 0) {
        const int o = nt * 16 + ml;
        const float a2o1 = a2[o], a2o2 = a2[64 + o];
        #pragma unroll
        for (int r = 0; r < 4; ++r) {
            const float wv2 = c2[r] + accH[nt][lane][r];
            wh2s[o * 20 + q * 4 + r] = f2bf(wv2);
            float p1 = wv2 * a2o1, p2 = wv2 * a2o2;
            p1 += __shfl_xor(p1, 1, 64); p2 += __shfl_xor(p2, 1, 64);
            p1 += __shfl_xor(p1, 2, 64); p2 += __shfl_xor(p2, 2, 64);
            p1 += __shfl_xor(p1, 4, 64); p2 += __shfl_xor(p2, 4, 64);
            p1 += __shfl_xor(p1, 8, 64); p2 += __shfl_xor(p2, 8, 64);
            if (ml == 0) {
                fp1[nt][q * 4 + r] = p1;
                fp2[nt][q * 4 + r] = p2;
            }
        }
    }
    __syncthreads();
    if (t < 256) {
        const int o = t >> 2, seg = t & 3;
        *(uint2*)&whbt_out[((size_t)(b * 64 + o)) * 512 + i0 + seg * 4] =
            *(const uint2*)&wh2s[o * 20 + seg * 4];
    }
    if (t < 16) {
        f1out[b * 512 + i0 + t] = fp1[0][t] + fp1[1][t] + fp1[2][t] + fp1[3][t];
        f2out[b * 512 + i0 + t] = fp2[0][t] + fp2[1][t] + fp2[2][t] + fp2[3][t];
    }
}

// ---------------------------------------------------------------------------
// Kernel: edge MLP via MFMA, 16 edges/block, prepacked fc1 B-fragments
// ---------------------------------------------------------------------------
#define FSTR 136
__global__ __launch_bounds__(256) void edge_mlp_kernel(
    const float* __restrict__ hg,       // (4096, 64)
    const int* __restrict__ eidx,       // (2048, 2)
    const u16* __restrict__ efw,        // prepacked fc1 B-frags
    const float* __restrict__ fc1b,     // (64,)
    const float* __restrict__ fc2w,     // (64, 1)
    const float* __restrict__ fc2b,     // (1,)
    float* __restrict__ out)            // (8, 2048)
{
    __shared__ __align__(16) u16 he[16 * FSTR];
    __shared__ float part[16][4];

    const int t   = threadIdx.x;
    const int blk = blockIdx.x;
    const int b   = blk >> 7;
    const int e0  = (blk & 127) * 16;
    const int lane = t & 63, wv = t >> 6, ml = lane & 15, q = lane >> 4;

    short8 bw[4];
    #pragma unroll
    for (int ks = 0; ks < 4; ++ks)
        bw[ks] = *(const short8*)(efw + ((ks * 4 + wv) * 64 + lane) * 8);
    const int o = 16 * wv + ml;
    const float bo = fc1b[o];
    const float wo = fc2w[o];

    {
        const int ep = t >> 4, p = t & 15;
        const int e = e0 + ep;
        const int node = (p < 8) ? eidx[e * 2] : eidx[e * 2 + 1];
        const int c0 = (p & 7) * 8;
        const float* hp = hg + ((size_t)(b * 512 + node)) * 64 + c0;
        const float4 fa = *(const float4*)hp;
        const float4 fb = *(const float4*)(hp + 4);
        unsigned int* dst = (unsigned int*)&he[ep * FSTR + ((p < 8) ? 0 : 64) + c0];
        dst[0] = pk2(fa.x, fa.y);
        dst[1] = pk2(fa.z, fa.w);
        dst[2] = pk2(fb.x, fb.y);
        dst[3] = pk2(fb.z, fb.w);
    }
    __syncthreads();

    float4v acc = {0.f, 0.f, 0.f, 0.f};
    #pragma unroll
    for (int ks = 0; ks < 4; ++ks) {
        const short8 afr = *(const short8*)&he[ml * FSTR + ks * 32 + q * 8];
        acc = __builtin_amdgcn_mfma_f32_16x16x32_bf16(afr, bw[ks], acc, 0, 0, 0);
    }
    #pragma unroll
    for (int r = 0; r < 4; ++r) {
        float z = fmaxf(acc[r] + bo, 0.f) * wo;
        z += __shfl_xor(z, 1, 64);
        z += __shfl_xor(z, 2, 64);
        z += __shfl_xor(z, 4, 64);
        z += __shfl_xor(z, 8, 64);
        if (ml == 0) part[q * 4 + r][wv] = z;
    }
    __syncthreads();
    if (t < 16) {
        const float v = part[t][0] + part[t][1] + part[t][2] + part[t][3] + fc2b[0];
        out[b * 2048 + e0 + t] = 1.0f / (1.0f + __expf(-v));
    }
}

// ---------------------------------------------------------------------------
extern "C" void kernel_launch(void* const* d_in, const int* in_sizes, int n_in,
                              void* d_out, int out_size, void* d_ws, size_t ws_size,
                              hipStream_t stream) {
    const float* x    = (const float*)d_in[0];
    const int* adj    = (const int*)d_in[1];
    const int* eidx   = (const int*)d_in[2];
    const float* w1   = (const float*)d_in[3];
    const float* b1   = (const float*)d_in[4];
    const float* w2   = (const float*)d_in[5];
    const float* b2   = (const float*)d_in[6];
    const float* W1   = (const float*)d_in[7];
    const float* a1   = (const float*)d_in[8];
    const float* W2   = (const float*)d_in[9];
    const float* a2   = (const float*)d_in[10];
    const float* fc1w = (const float*)d_in[11];
    const float* fc1b = (const float*)d_in[12];
    const float* fc2w = (const float*)d_in[13];
    const float* fc2b = (const float*)d_in[14];
    float* out = (float*)d_out;

    float* ws = (float*)d_ws;
    const size_t R = (size_t)BATCH * NNODE;       // 4096
    float* g     = ws;                            // R*64 f32 (layer-2 out)
    float* f1a   = g + R * 64;                    // R
    float* f2a   = f1a + R;                       // R
    float* f1b   = f2a + R;                       // R
    float* f2b   = f1b + R;                       // R
    u16*   whbt1 = (u16*)(f2b + R);               // R*64
    u16*   whbt2 = whbt1 + R * 64;                // R*64
    u16*   w2f   = whbt2 + R * 64;                // 10240
    u16*   efw   = w2f + 10240;                   // 8192
    u16*   w2gf  = efw + 8192;                    // 4096
    u16*   msk   = w2gf + 4096;                   // 16384 u16 (32 KB)

    pre_kernel<<<dim3(67), dim3(256), 0, stream>>>(
        adj, w2, fc1w, W2, w2f, efw, w2gf, msk);
    conv_fused_kernel<<<dim3(2048), dim3(256), 0, stream>>>(
        x, w1, b1, b2, W1, a1, w2f, whbt1, f1a, f2a);
    gat_attn_kernel<<<dim3(256), dim3(512), 0, stream>>>(
        whbt1, f1a, f2a, msk, w2gf, a2, whbt2, f1b, f2b, g, 1);
    gat_attn_kernel<<<dim3(256), dim3(512), 0, stream>>>(
        whbt2, f1b, f2b, msk, w2gf, a2, whbt2, f1b, f2b, g, 0);
    edge_mlp_kernel<<<dim3(1024), dim3(256), 0, stream>>>(
        g, eidx, efw, fc1b, fc2w, fc2b, out);
}